// Round 1
// baseline (331.991 us; speedup 1.0000x reference)
//
#include <hip/hip_runtime.h>

// ValenceConstraint: bond-count scatter + valence violation penalty scaling.
// Inputs: d_in[0]=h fp32 [N*D], d_in[1]=edge_index int32 [2*E] (row-major:
// first E = rows), d_in[2]=atom_types int32 [N].
// Output: d_out = [h_new (N*D fp32) | constraint_loss (1 fp32)].
// Workspace: counts (N int32) | accum (1 fp32).

__device__ __forceinline__ float max_valence(int z) {
    // valence table: default 4, overrides {1:1,6:4,7:3,8:2,9:1,15:5,16:6,17:7}
    switch (z) {
        case 1:  return 1.0f;
        case 6:  return 4.0f;
        case 7:  return 3.0f;
        case 8:  return 2.0f;
        case 9:  return 1.0f;
        case 15: return 5.0f;
        case 16: return 6.0f;
        case 17: return 7.0f;
        default: return 4.0f;
    }
}

__global__ void vc_count_kernel(const int* __restrict__ row, int E,
                                int* __restrict__ counts) {
    int t = blockIdx.x * blockDim.x + threadIdx.x;
    int base = t * 4;
    if (base + 3 < E) {
        int4 r = *reinterpret_cast<const int4*>(row + base);
        atomicAdd(&counts[r.x], 1);
        atomicAdd(&counts[r.y], 1);
        atomicAdd(&counts[r.z], 1);
        atomicAdd(&counts[r.w], 1);
    } else {
        for (int i = base; i < E; ++i) atomicAdd(&counts[row[i]], 1);
    }
}

__global__ void vc_reduce_kernel(const int* __restrict__ counts,
                                 const int* __restrict__ types, int N,
                                 float* __restrict__ accum) {
    int t = blockIdx.x * blockDim.x + threadIdx.x;
    float v = 0.0f;
    if (t < N) {
        float c = (float)counts[t];
        v = fmaxf(c - max_valence(types[t]), 0.0f);
    }
    // wave64 butterfly reduce
    #pragma unroll
    for (int off = 32; off > 0; off >>= 1) v += __shfl_down(v, off, 64);
    __shared__ float s[4];
    int lane = threadIdx.x & 63;
    int w = threadIdx.x >> 6;
    if (lane == 0) s[w] = v;
    __syncthreads();
    if (threadIdx.x == 0) {
        float tot = s[0] + s[1] + s[2] + s[3];
        atomicAdd(accum, tot);
    }
}

__global__ void vc_loss_kernel(const float* __restrict__ accum,
                               float* __restrict__ out_loss, float scale) {
    *out_loss = (*accum) * scale;
}

// One thread per float4 of h. Consecutive 64 threads (for D=256) share a row,
// so counts/types loads broadcast within the wave.
__global__ void vc_scale_kernel(const float4* __restrict__ h,
                                const int* __restrict__ counts,
                                const int* __restrict__ types,
                                float4* __restrict__ out,
                                int nquads, int qpr) {
    int t = blockIdx.x * blockDim.x + threadIdx.x;
    if (t >= nquads) return;
    int row = (qpr == 64) ? (t >> 6) : (t / qpr);
    float c = (float)counts[row];
    float viol = fmaxf(c - max_valence(types[row]), 0.0f);
    float p = (viol > 0.0f) ? (1.0f - viol * 0.1f) : 1.0f;
    float4 x = h[t];
    x.x *= p; x.y *= p; x.z *= p; x.w *= p;
    out[t] = x;
}

extern "C" void kernel_launch(void* const* d_in, const int* in_sizes, int n_in,
                              void* d_out, int out_size, void* d_ws, size_t ws_size,
                              hipStream_t stream) {
    const float* h          = (const float*)d_in[0];
    const int*   edge_index = (const int*)d_in[1];
    const int*   atom_types = (const int*)d_in[2];

    const int N = in_sizes[2];
    const int D = in_sizes[0] / N;   // 256
    const int E = in_sizes[1] / 2;   // edge_index is (2, E); rows are first E

    int*   counts = (int*)d_ws;
    float* accum  = (float*)((char*)d_ws + (size_t)N * sizeof(int));

    float* out_h    = (float*)d_out;
    float* out_loss = out_h + (size_t)N * D;

    // zero counts + accumulator (ws is poisoned 0xAA before every call)
    hipMemsetAsync(d_ws, 0, (size_t)(N + 1) * sizeof(int), stream);

    // 1) bond counts: scatter-add over edge rows (int4-vectorized loads)
    {
        int nthreads = (E + 3) / 4;
        int blocks = (nthreads + 255) / 256;
        vc_count_kernel<<<blocks, 256, 0, stream>>>(edge_index, E, counts);
    }

    // 2) violation sum -> accum
    {
        int blocks = (N + 255) / 256;
        vc_reduce_kernel<<<blocks, 256, 0, stream>>>(counts, atom_types, N, accum);
    }

    // 3) loss = (sum / N) * 0.05
    vc_loss_kernel<<<1, 1, 0, stream>>>(accum, out_loss, 0.05f / (float)N);

    // 4) h_new = h * penalty (float4 vectorized, memory-bound)
    {
        int nquads = (N * D) / 4;
        int qpr = D / 4;
        int blocks = (nquads + 255) / 256;
        vc_scale_kernel<<<blocks, 256, 0, stream>>>(
            (const float4*)h, counts, atom_types, (float4*)out_h, nquads, qpr);
    }
}